// Round 6
// baseline (1067.385 us; speedup 1.0000x reference)
//
#include <hip/hip_runtime.h>
#include <cstdint>
#include <cstddef>

typedef unsigned long long u64;
typedef unsigned int u32;
typedef __attribute__((ext_vector_type(8))) short short8;
typedef __attribute__((ext_vector_type(4))) float f32x4;

#define NBOX 100800
#define CAND_CAP 4096
#define BPAD 36   // hood pixel stride (shorts)

// ---------------- workspace layout (bytes) ----------------
#define OFF_WTH0 ((size_t)0)
#define OFF_WTH1 ((size_t)18874368)
#define OFF_WTH2 ((size_t)23592960)
#define OFF_WTL0 ((size_t)24772608)
#define OFF_WTL1 ((size_t)43646976)
#define OFF_WTL2 ((size_t)48365568)
#define OFF_Y0   ((size_t)49545216)
#define OFF_Y1   ((size_t)56098816)
#define OFF_Y2   ((size_t)69206016)
#define OFF_KEYS ((size_t)95420416)
#define OFF_HIST ((size_t)96226816)   // 262144
#define OFF_META ((size_t)96488960)   // 64
#define OFF_LOG  ((size_t)96489024)   // 403200
#define OFF_CAND ((size_t)96892224)   // 32768
#define OFF_SEL  ((size_t)96924992)   // 1024
#define OFF_CS2  ((size_t)96926016)   // 1024 (select stage-1 partials)
#define OFF_XTH0 ((size_t)96927040)
#define OFF_XTH1 ((size_t)100203840)
#define OFF_XTH2 ((size_t)106757440)
#define OFF_XTL0 ((size_t)119864640)
#define OFF_XTL1 ((size_t)123141440)
#define OFF_XTL2 ((size_t)129695040)
#define NEED_FULL ((size_t)142802240)
#define MEMSET_LEN ((size_t)(262144 + 64 + 403200))

// ---------------- bf16 helpers (RNE, finite inputs) ----------------
__device__ __forceinline__ short f2bf(float f) {
    u32 u = __float_as_uint(f);
    u = (u + 0x7fffu + ((u >> 16) & 1u)) >> 16;
    return (short)u;
}
__device__ __forceinline__ float bf2f(short h) {
    return __uint_as_float(((u32)(unsigned short)h) << 16);
}

// ---------------- merged prep: weights + input transpose ----------------
struct PrepW { const float* w; short* wh; short* wl; int C, bbase; };
struct PrepXs { const float* x; short* xh; short* xl; int C, HW, bbase, ptiles; };

__global__ __launch_bounds__(256) void prep_all(
    PrepW w0, PrepW w1, PrepW w2, PrepXs p0, PrepXs p1, PrepXs p2, int use_xt)
{
    __shared__ float ws_[2304];
    __shared__ short th[32][34];
    __shared__ short tl[32][34];
    int b = blockIdx.x;
    if (b < 5376) {
        PrepW pw = (b >= (u32)w2.bbase) ? w2 : (b >= (u32)w1.bbase) ? w1 : w0;
        int local = b - pw.bbase;
        int chunks = pw.C >> 8;
        int co = local / chunks;
        int ci0 = (local % chunks) << 8;
        size_t base = ((size_t)co * pw.C + ci0) * 9;
        for (int idx = threadIdx.x; idx < 2304; idx += 256) ws_[idx] = pw.w[base + idx];
        __syncthreads();
        for (int idx = threadIdx.x; idx < 2304; idx += 256) {
            int tap = idx >> 8, ci = idx & 255;
            float v = ws_[ci * 9 + tap];
            short h = f2bf(v);
            short l = f2bf(v - bf2f(h));
            size_t o = ((size_t)co * 9 + tap) * pw.C + ci0 + ci;
            pw.wh[o] = h; pw.wl[o] = l;
        }
    } else if (use_xt) {
        PrepXs p = (b >= (u32)p2.bbase) ? p2 : (b >= (u32)p1.bbase) ? p1 : p0;
        int local = b - p.bbase;
        int pt = local % p.ptiles, ct = local / p.ptiles;
        for (int idx = threadIdx.x; idx < 1024; idx += 256) {
            int ci = idx >> 5, px = idx & 31;
            float v = p.x[(size_t)(ct * 32 + ci) * p.HW + pt * 32 + px];
            short h = f2bf(v);
            th[ci][px] = h;
            tl[ci][px] = f2bf(v - bf2f(h));
        }
        __syncthreads();
        for (int idx = threadIdx.x; idx < 1024; idx += 256) {
            int px = idx >> 5, ci = idx & 31;
            size_t o = (size_t)(pt * 32 + px) * p.C + ct * 32 + ci;
            p.xh[o] = th[ci][px];
            p.xl[o] = tl[ci][px];
        }
    }
}

// ------- fused 3-head 3x3 conv, bf16 MFMA hi/lo 3-pass -----------------------
// A fragments loaded DIRECTLY from global (weights are in exact frag layout;
// L2-resident via XCD swizzle). Hood (B) single-buffered in LDS, read-only
// across all 9 taps -> only 2 barriers per 32-channel chunk. Next-chunk hood
// loads issued into registers a full tap-loop ahead (latency hidden).
struct ConvHead {
    const float* x; const short* xh; const short* xl;
    const short* wh; const short* wl; const float* bias;
    const float* w1; float* y;
    int C, H, W, sx, nco_mask, nco_shift, chunks, bbase, lbase;
};

__global__ __launch_bounds__(256, 2) void conv3x3_mfma(
    ConvHead h0, ConvHead h1, ConvHead h2, float* __restrict__ logits, int use_xt)
{
    ConvHead h = (blockIdx.x >= (u32)h2.bbase) ? h2 :
                 (blockIdx.x >= (u32)h1.bbase) ? h1 : h0;
    const int local = blockIdx.x - h.bbase;
    const int my = local & h.nco_mask;
    const int sp = local >> h.nco_shift;
    const int ty = sp / h.sx;
    const int tx = sp - ty * h.sx;
    const int py0 = ty * 8, px0 = tx * 16;
    const int co0 = my * 128;
    const int C = h.C, H = h.H, W = h.W, HW = H * W;

    const int tid = threadIdx.x;
    const int lane = tid & 63;
    const int wave = tid >> 6;
    const int quad = lane >> 4;
    const int l15 = lane & 15;
    const int wm = wave >> 1, wn = wave & 1;

    __shared__ short Bh_hi[180 * BPAD];
    __shared__ short Bh_lo[180 * BPAD];
    __shared__ float wobj[3][128];

    // stage objectness weight rows once (visible after first chunk barrier)
    for (int idx = tid; idx < 384; idx += 256) {
        int a = idx >> 7, m = idx & 127;
        wobj[a][m] = h.w1[(size_t)(a * 85 + 4) * C + co0 + m];
    }

    f32x4 acc[4][4];
    #pragma unroll
    for (int i = 0; i < 4; i++)
        #pragma unroll
        for (int j = 0; j < 4; j++) acc[i][j] = (f32x4){0.f, 0.f, 0.f, 0.f};

    // hood unit metadata: 1440 units of 16B (180 px x 4 k-quads x {hi,lo})
    // um1: pix(0:19) | q(20:21) | arr(22) | inb(23) | ok(24);  um2: lds offset
    int um1[6], um2[6];
    #pragma unroll
    for (int i = 0; i < 6; i++) {
        int v = tid + (i << 8);
        int ok = (v < 1440) ? 1 : 0;
        int arr = (v >= 720) ? 1 : 0;
        int u = v - (arr ? 720 : 0);
        int hp = (u >> 2) % 180;
        int q = u & 3;
        int hy = hp / 18, hx = hp - hy * 18;
        int gy = py0 - 1 + hy, gx = px0 - 1 + hx;
        int inb = (ok && gy >= 0 && gy < H && gx >= 0 && gx < W) ? 1 : 0;
        int pix = inb ? (gy * W + gx) : 0;
        um1[i] = pix | (q << 20) | (arr << 22) | (inb << 23) | (ok << 24);
        um2[i] = hp * BPAD + q * 8;
    }
    // B frag base offsets (per nt), tap adds a compile-time-constant offset
    int vb[4];
    #pragma unroll
    for (int nt = 0; nt < 4; nt++) {
        int n = wn * 64 + nt * 16 + l15;
        vb[nt] = ((n >> 4) * 18 + (n & 15)) * BPAD + quad * 8;
    }

    short8 hreg[6];
    auto load_units = [&](int ci0) {
        #pragma unroll
        for (int i = 0; i < 6; i++) {
            short8 r = {0,0,0,0,0,0,0,0};
            if ((um1[i] >> 23) & 1) {
                int pix = um1[i] & 0xFFFFF;
                int q   = (um1[i] >> 20) & 3;
                int arr = (um1[i] >> 22) & 1;
                if (use_xt) {
                    const short* gp = (arr ? h.xl : h.xh) + (size_t)pix * C + ci0 + q * 8;
                    r = *(const short8*)gp;
                } else {
                    const float* fp = h.x + (size_t)(ci0 + q * 8) * HW + pix;
                    #pragma unroll
                    for (int k = 0; k < 8; k++) {
                        float vv = fp[(size_t)k * HW];
                        short hh = f2bf(vv);
                        r[k] = arr ? f2bf(vv - bf2f(hh)) : hh;
                    }
                }
            }
            hreg[i] = r;
        }
    };

    load_units(0);
    for (int ch = 0; ch < h.chunks; ++ch) {
        const int ci0 = ch << 5;
        __syncthreads();   // previous chunk's hood reads complete
        #pragma unroll
        for (int i = 0; i < 6; i++) {
            if ((um1[i] >> 24) & 1) {
                short* dst = (((um1[i] >> 22) & 1) ? Bh_lo : Bh_hi) + um2[i];
                *(short8*)dst = hreg[i];
            }
        }
        __syncthreads();   // hood visible
        if (ch + 1 < h.chunks) load_units(ci0 + 32);   // fire next-chunk loads

        #pragma unroll
        for (int tap = 0; tap < 9; ++tap) {
            const int dy = tap / 3, dx = tap - dy * 3;
            const int hoff = (dy * 18 + dx) * BPAD;
            short8 ah[4], al[4], bh[4], bl[4];
            #pragma unroll
            for (int mt = 0; mt < 4; mt++) {
                size_t off = ((size_t)(co0 + wm * 64 + mt * 16 + l15) * 9 + tap) * C
                             + ci0 + quad * 8;
                ah[mt] = *(const short8*)(h.wh + off);
                al[mt] = *(const short8*)(h.wl + off);
            }
            #pragma unroll
            for (int nt = 0; nt < 4; nt++) {
                bh[nt] = *(const short8*)&Bh_hi[vb[nt] + hoff];
                bl[nt] = *(const short8*)&Bh_lo[vb[nt] + hoff];
            }
            #pragma unroll
            for (int mt = 0; mt < 4; mt++)
                #pragma unroll
                for (int nt = 0; nt < 4; nt++) {
                    acc[mt][nt] = __builtin_amdgcn_mfma_f32_16x16x32_bf16(ah[mt], bh[nt], acc[mt][nt], 0, 0, 0);
                    acc[mt][nt] = __builtin_amdgcn_mfma_f32_16x16x32_bf16(ah[mt], bl[nt], acc[mt][nt], 0, 0, 0);
                    acc[mt][nt] = __builtin_amdgcn_mfma_f32_16x16x32_bf16(al[mt], bh[nt], acc[mt][nt], 0, 0, 0);
                }
        }
    }

    // ---- epilogue: y = acc + bias; fused objectness partial dot ----
    #pragma unroll
    for (int nt = 0; nt < 4; nt++) {
        int n = wn * 64 + nt * 16 + l15;
        int py = py0 + (n >> 4), px = px0 + (n & 15);
        if (px < W) {
            int p = py * W + px;
            float s0 = 0.f, s1 = 0.f, s2 = 0.f;
            #pragma unroll
            for (int mt = 0; mt < 4; mt++) {
                #pragma unroll
                for (int r = 0; r < 4; r++) {
                    int m = wm * 64 + mt * 16 + quad * 4 + r;
                    int co = co0 + m;
                    float yv = acc[mt][nt][r] + h.bias[co];
                    h.y[(size_t)co * HW + p] = yv;
                    s0 = fmaf(yv, wobj[0][m], s0);
                    s1 = fmaf(yv, wobj[1][m], s1);
                    s2 = fmaf(yv, wobj[2][m], s2);
                }
            }
            atomicAdd(&logits[h.lbase + p], s0);
            atomicAdd(&logits[h.lbase + HW + p], s1);
            atomicAdd(&logits[h.lbase + 2 * HW + p], s2);
        }
    }
}

// ---------------- keys: logits -> sigmoid -> sort key + histogram ------------
__global__ __launch_bounds__(256) void keys_kernel(
    const float* __restrict__ logits,
    const float* __restrict__ b10, const float* __restrict__ b11, const float* __restrict__ b12,
    u64* __restrict__ keys, u32* __restrict__ hist)
{
    int i = blockIdx.x * 256 + threadIdx.x;
    if (i >= NBOX) return;
    float bias;
    if (i < 4800)       bias = b10[(i / 1600) * 85 + 4];
    else if (i < 24000) bias = b11[((i - 4800) / 6400) * 85 + 4];
    else                bias = b12[((i - 24000) / 25600) * 85 + 4];
    float s = 1.0f / (1.0f + expf(-(logits[i] + bias)));
    u64 k = ((u64)__float_as_uint(s) << 32) | (u64)(0xFFFFFFFFu - (u32)i);
    keys[i] = k;
    atomicAdd(&hist[(u32)(k >> 48)], 1u);
}

// ---------------- top-256 selection: parallel 2-stage ----------------
__global__ __launch_bounds__(256) void select1_kernel(const u32* __restrict__ hist,
                                                      u32* __restrict__ csum2)
{
    __shared__ u32 red[256];
    int t = threadIdx.x;
    red[t] = hist[blockIdx.x * 256 + t];
    __syncthreads();
    for (int s = 128; s > 0; s >>= 1) {
        if (t < s) red[t] += red[t + s];
        __syncthreads();
    }
    if (t == 0) csum2[blockIdx.x] = red[0];
}

__global__ __launch_bounds__(256) void select2_kernel(const u32* __restrict__ hist,
                                                      const u32* __restrict__ csum2,
                                                      u32* __restrict__ meta)
{
    __shared__ u32 cs[256];
    __shared__ u32 hb[256];
    __shared__ int sh_chunk;
    __shared__ u32 sh_cum;
    int t = threadIdx.x;
    cs[t] = csum2[t];
    __syncthreads();
    if (t == 0) {
        u32 cum = 0; int chunk = 255;
        for (; chunk > 0; chunk--) {
            if (cum + cs[chunk] >= 256u) break;
            cum += cs[chunk];
        }
        sh_chunk = chunk; sh_cum = cum;
    }
    __syncthreads();
    hb[t] = hist[sh_chunk * 256 + t];
    __syncthreads();
    if (t == 0) {
        int chunk = sh_chunk;
        u32 cumAbove = sh_cum;
        int B = chunk * 256;
        for (int bb = 255; bb >= 0; bb--) {
            u32 hv = hb[bb];
            if (cumAbove + hv >= 256u) { B = chunk * 256 + bb; break; }
            cumAbove += hv;
        }
        meta[0] = (u32)B;
        meta[1] = cumAbove;
    }
}

__global__ __launch_bounds__(256) void compact_kernel(
    const u64* __restrict__ keys, int n, const u32* __restrict__ meta,
    u64* __restrict__ cand, u32* __restrict__ count)
{
    int i = blockIdx.x * blockDim.x + threadIdx.x;
    if (i < n) {
        u64 k = keys[i];
        if ((u32)(k >> 48) >= meta[0]) {
            u32 pos = atomicAdd(count, 1u);
            if (pos < CAND_CAP) cand[pos] = k;
        }
    }
}

__global__ __launch_bounds__(1024) void sort_select_kernel(
    const u64* __restrict__ cand, const u32* __restrict__ meta,
    u32* __restrict__ sel)
{
    __shared__ u64 sk[CAND_CAP];
    int n = (int)meta[2];
    if (n > CAND_CAP) n = CAND_CAP;
    for (int i = threadIdx.x; i < CAND_CAP; i += 1024)
        sk[i] = (i < n) ? cand[i] : 0ull;
    __syncthreads();
    for (int k = 2; k <= CAND_CAP; k <<= 1) {
        for (int j = k >> 1; j > 0; j >>= 1) {
            for (int i = threadIdx.x; i < CAND_CAP; i += 1024) {
                int ixj = i ^ j;
                if (ixj > i) {
                    u64 a = sk[i], c = sk[ixj];
                    bool sw = ((i & k) == 0) ? (a > c) : (a < c);
                    if (sw) { sk[i] = c; sk[ixj] = a; }
                }
            }
            __syncthreads();
        }
    }
    if (threadIdx.x < 256) {
        u64 k = sk[CAND_CAP - 1 - threadIdx.x];
        sel[threadIdx.x] = 0xFFFFFFFFu - (u32)(k & 0xFFFFFFFFull);
    }
}

// ----- final: 85-ch 1x1 conv + decode for winners, wave-per-channel GEMV -----
__global__ __launch_bounds__(256) void final_kernel(
    const float* __restrict__ y0, const float* __restrict__ y1, const float* __restrict__ y2,
    const float* __restrict__ w10, const float* __restrict__ w11, const float* __restrict__ w12,
    const float* __restrict__ b10, const float* __restrict__ b11, const float* __restrict__ b12,
    const u32* __restrict__ sel, float* __restrict__ out)
{
    int b = blockIdx.x;
    u32 bi = sel[b];
    const float *y, *w1, *b1;
    int C, H, W, base; float ratio;
    float anchs[6];
    if (bi < 4800u) {
        y = y0; w1 = w10; b1 = b10; C = 1024; H = 40; W = 40; base = 0; ratio = 32.f;
        anchs[0]=116.f; anchs[1]=90.f; anchs[2]=156.f; anchs[3]=198.f; anchs[4]=373.f; anchs[5]=326.f;
    } else if (bi < 24000u) {
        y = y1; w1 = w11; b1 = b11; C = 512; H = 80; W = 80; base = 4800; ratio = 16.f;
        anchs[0]=30.f; anchs[1]=61.f; anchs[2]=62.f; anchs[3]=45.f; anchs[4]=59.f; anchs[5]=119.f;
    } else {
        y = y2; w1 = w12; b1 = b12; C = 256; H = 160; W = 160; base = 24000; ratio = 8.f;
        anchs[0]=10.f; anchs[1]=13.f; anchs[2]=16.f; anchs[3]=30.f; anchs[4]=33.f; anchs[5]=23.f;
    }
    int HW = H * W;
    int r = (int)bi - base;
    int a = r / HW, p = r % HW;
    __shared__ float ys[1024];
    for (int ci = threadIdx.x; ci < C; ci += 256)
        ys[ci] = y[(size_t)ci * HW + p];
    __syncthreads();
    int wv = threadIdx.x >> 6, ln = threadIdx.x & 63;
    int py = p / W, px = p - (p / W) * W;
    for (int c = wv; c < 85; c += 4) {
        const float* wrow = w1 + (size_t)(a * 85 + c) * C;
        float s = 0.f;
        for (int ci = ln; ci < C; ci += 64) s = fmaf(ys[ci], wrow[ci], s);
        #pragma unroll
        for (int off = 32; off > 0; off >>= 1) s += __shfl_down(s, off, 64);
        if (ln == 0) {
            float v = s + b1[a * 85 + c];
            float sg = 1.0f / (1.0f + expf(-v));
            float o;
            if (c == 0)      o = (sg * 2.0f - 0.5f + (float)px) * ratio;
            else if (c == 1) o = (sg * 2.0f - 0.5f + (float)py) * ratio;
            else if (c == 2) { float t = sg * 2.0f; o = t * t * anchs[a * 2]; }
            else if (c == 3) { float t = sg * 2.0f; o = t * t * anchs[a * 2 + 1]; }
            else             o = sg;
            out[(size_t)b * 85 + c] = o;
        }
    }
}

// ---------------- launch ----------------
extern "C" void kernel_launch(void* const* d_in, const int* in_sizes, int n_in,
                              void* d_out, int out_size, void* d_ws, size_t ws_size,
                              hipStream_t stream)
{
    const float* feat0 = (const float*)d_in[0];   // (256,160,160)
    const float* feat1 = (const float*)d_in[1];   // (512,80,80)
    const float* feat2 = (const float*)d_in[2];   // (1024,40,40)
    const float* w3_0 = (const float*)d_in[3];  const float* b3_0 = (const float*)d_in[4];
    const float* w1_0 = (const float*)d_in[5];  const float* b1_0 = (const float*)d_in[6];
    const float* w3_1 = (const float*)d_in[7];  const float* b3_1 = (const float*)d_in[8];
    const float* w1_1 = (const float*)d_in[9];  const float* b1_1 = (const float*)d_in[10];
    const float* w3_2 = (const float*)d_in[11]; const float* b3_2 = (const float*)d_in[12];
    const float* w1_2 = (const float*)d_in[13]; const float* b1_2 = (const float*)d_in[14];

    char* ws = (char*)d_ws;
    short* wth0 = (short*)(ws + OFF_WTH0);
    short* wth1 = (short*)(ws + OFF_WTH1);
    short* wth2 = (short*)(ws + OFF_WTH2);
    short* wtl0 = (short*)(ws + OFF_WTL0);
    short* wtl1 = (short*)(ws + OFF_WTL1);
    short* wtl2 = (short*)(ws + OFF_WTL2);
    float* y0   = (float*)(ws + OFF_Y0);
    float* y1   = (float*)(ws + OFF_Y1);
    float* y2   = (float*)(ws + OFF_Y2);
    u64*   keys = (u64*)  (ws + OFF_KEYS);
    u32*   hist = (u32*)  (ws + OFF_HIST);
    u32*   meta = (u32*)  (ws + OFF_META);
    float* logits = (float*)(ws + OFF_LOG);
    u64*   cand = (u64*)  (ws + OFF_CAND);
    u32*   sel  = (u32*)  (ws + OFF_SEL);
    u32*   cs2  = (u32*)  (ws + OFF_CS2);

    const int use_xt = (ws_size >= NEED_FULL) ? 1 : 0;
    short* xth0 = (short*)(ws + OFF_XTH0);
    short* xth1 = (short*)(ws + OFF_XTH1);
    short* xth2 = (short*)(ws + OFF_XTH2);
    short* xtl0 = (short*)(ws + OFF_XTL0);
    short* xtl1 = (short*)(ws + OFF_XTL1);
    short* xtl2 = (short*)(ws + OFF_XTL2);

    hipMemsetAsync(ws + OFF_HIST, 0, MEMSET_LEN, stream);

    // merged prep: weights (blocks 0..5375) + input transpose (5376..16575)
    {
        PrepW pw0 = {w3_0, wth0, wtl0, 1024, 0};
        PrepW pw1 = {w3_1, wth1, wtl1, 512,  4096};
        PrepW pw2 = {w3_2, wth2, wtl2, 256,  5120};
        PrepXs px0 = {feat2, xth0, xtl0, 1024, 1600,  5376,  50};
        PrepXs px1 = {feat1, xth1, xtl1, 512,  6400,  6976,  200};
        PrepXs px2 = {feat0, xth2, xtl2, 256,  25600, 10176, 800};
        prep_all<<<16576, 256, 0, stream>>>(pw0, pw1, pw2, px0, px1, px2, use_xt);
    }

    // fused 3-head 3x3 conv (+ objectness partials)
    ConvHead h0 = {feat2, xth0, xtl0, wth0, wtl0, b3_0, w1_0, y0, 1024, 40,  40,  3,  7, 3, 32, 0,   0};
    ConvHead h1 = {feat1, xth1, xtl1, wth1, wtl1, b3_1, w1_1, y1, 512,  80,  80,  5,  3, 2, 16, 120, 4800};
    ConvHead h2 = {feat0, xth2, xtl2, wth2, wtl2, b3_2, w1_2, y2, 256,  160, 160, 10, 1, 1, 8,  320, 24000};
    conv3x3_mfma<<<720, 256, 0, stream>>>(h0, h1, h2, logits, use_xt);

    // keys + histogram from logits
    keys_kernel<<<(NBOX + 255) / 256, 256, 0, stream>>>(logits, b1_0, b1_1, b1_2, keys, hist);

    // top-256
    select1_kernel<<<256, 256, 0, stream>>>(hist, cs2);
    select2_kernel<<<1, 256, 0, stream>>>(hist, cs2, meta);
    compact_kernel<<<(NBOX + 255) / 256, 256, 0, stream>>>(keys, NBOX, meta, cand, meta + 2);
    sort_select_kernel<<<1, 1024, 0, stream>>>(cand, meta, sel);

    // full 85-channel compute + decode for winners only
    final_kernel<<<256, 256, 0, stream>>>(y0, y1, y2, w1_0, w1_1, w1_2,
                                          b1_0, b1_1, b1_2, sel, (float*)d_out);
}

// Round 7
// 777.235 us; speedup vs baseline: 1.3733x; 1.3733x over previous
//
#include <hip/hip_runtime.h>
#include <cstdint>
#include <cstddef>

typedef unsigned long long u64;
typedef unsigned int u32;
typedef __attribute__((ext_vector_type(8))) short short8;
typedef __attribute__((ext_vector_type(4))) float f32x4;

#define NBOX 100800
#define CAND_CAP 4096
#define APAD 36   // A row stride (shorts), 8B-aligned rows, 4-way banks max
#define BPAD 36   // hood pixel stride (shorts)

// ---------------- workspace layout (bytes) ----------------
#define OFF_WTH0 ((size_t)0)
#define OFF_WTH1 ((size_t)18874368)
#define OFF_WTH2 ((size_t)23592960)
#define OFF_WTL0 ((size_t)24772608)
#define OFF_WTL1 ((size_t)43646976)
#define OFF_WTL2 ((size_t)48365568)
#define OFF_Y0   ((size_t)49545216)
#define OFF_Y1   ((size_t)56098816)
#define OFF_Y2   ((size_t)69206016)
#define OFF_KEYS ((size_t)95420416)
#define OFF_HIST ((size_t)96226816)   // 262144
#define OFF_META ((size_t)96488960)   // 64
#define OFF_LOG  ((size_t)96489024)   // 403200
#define OFF_CAND ((size_t)96892224)   // 32768
#define OFF_SEL  ((size_t)96924992)   // 1024
#define OFF_CS2  ((size_t)96926016)   // 1024
#define OFF_XTH0 ((size_t)96927040)
#define OFF_XTH1 ((size_t)100203840)
#define OFF_XTH2 ((size_t)106757440)
#define OFF_XTL0 ((size_t)119864640)
#define OFF_XTL1 ((size_t)123141440)
#define OFF_XTL2 ((size_t)129695040)
#define NEED_FULL ((size_t)142802240)
#define MEMSET_LEN ((size_t)(262144 + 64 + 403200))

// ---------------- bf16 helpers (RNE, finite inputs) ----------------
__device__ __forceinline__ short f2bf(float f) {
    u32 u = __float_as_uint(f);
    u = (u + 0x7fffu + ((u >> 16) & 1u)) >> 16;
    return (short)u;
}
__device__ __forceinline__ float bf2f(short h) {
    return __uint_as_float(((u32)(unsigned short)h) << 16);
}

// ---------------- merged prep: weights + input transpose ----------------
struct PrepW { const float* w; short* wh; short* wl; int C, bbase; };
struct PrepXs { const float* x; short* xh; short* xl; int C, HW, bbase, ptiles; };

__global__ __launch_bounds__(256) void prep_all(
    PrepW w0, PrepW w1, PrepW w2, PrepXs p0, PrepXs p1, PrepXs p2, int use_xt)
{
    __shared__ float ws_[2304];
    __shared__ short th[32][34];
    __shared__ short tl[32][34];
    int b = blockIdx.x;
    if (b < 5376) {
        PrepW pw = (b >= (u32)w2.bbase) ? w2 : (b >= (u32)w1.bbase) ? w1 : w0;
        int local = b - pw.bbase;
        int chunks = pw.C >> 8;
        int co = local / chunks;
        int ci0 = (local % chunks) << 8;
        size_t base = ((size_t)co * pw.C + ci0) * 9;
        for (int idx = threadIdx.x; idx < 2304; idx += 256) ws_[idx] = pw.w[base + idx];
        __syncthreads();
        for (int idx = threadIdx.x; idx < 2304; idx += 256) {
            int tap = idx >> 8, ci = idx & 255;
            float v = ws_[ci * 9 + tap];
            short h = f2bf(v);
            short l = f2bf(v - bf2f(h));
            size_t o = ((size_t)co * 9 + tap) * pw.C + ci0 + ci;
            pw.wh[o] = h; pw.wl[o] = l;
        }
    } else if (use_xt) {
        PrepXs p = (b >= (u32)p2.bbase) ? p2 : (b >= (u32)p1.bbase) ? p1 : p0;
        int local = b - p.bbase;
        int pt = local % p.ptiles, ct = local / p.ptiles;
        for (int idx = threadIdx.x; idx < 1024; idx += 256) {
            int ci = idx >> 5, px = idx & 31;
            float v = p.x[(size_t)(ct * 32 + ci) * p.HW + pt * 32 + px];
            short h = f2bf(v);
            th[ci][px] = h;
            tl[ci][px] = f2bf(v - bf2f(h));
        }
        __syncthreads();
        for (int idx = threadIdx.x; idx < 1024; idx += 256) {
            int px = idx >> 5, ci = idx & 31;
            size_t o = (size_t)(pt * 32 + px) * p.C + ct * 32 + ci;
            p.xh[o] = th[ci][px];
            p.xl[o] = tl[ci][px];
        }
    }
}

// ------- fused 3-head 3x3 conv, bf16 MFMA hi/lo 3-pass -----------------------
// A double-buffered in LDS via register prefetch (global L2-resident through
// XCD co-tile swizzle): 1 barrier per tap (10/chunk vs R5's 19). Hood (B)
// single-buffered, register-prefetched a chunk ahead (R6 technique).
struct ConvHead {
    const float* x; const short* xh; const short* xl;
    const short* wh; const short* wl; const float* bias;
    const float* w1; float* y;
    int C, H, W, sx, nco_mask, nco_shift, chunks, bbase, lbase;
};

__global__ __launch_bounds__(256, 2) void conv3x3_mfma(
    ConvHead h0, ConvHead h1, ConvHead h2, float* __restrict__ logits, int use_xt)
{
    ConvHead h = (blockIdx.x >= (u32)h2.bbase) ? h2 :
                 (blockIdx.x >= (u32)h1.bbase) ? h1 : h0;
    const int local = blockIdx.x - h.bbase;
    const int my = local & h.nco_mask;
    const int sp = local >> h.nco_shift;
    const int ty = sp / h.sx;
    const int tx = sp - ty * h.sx;
    const int py0 = ty * 8, px0 = tx * 16;
    const int co0 = my * 128;
    const int C = h.C, H = h.H, W = h.W, HW = H * W;

    const int tid = threadIdx.x;
    const int lane = tid & 63;
    const int wave = tid >> 6;
    const int quad = lane >> 4;
    const int l15 = lane & 15;
    const int wm = wave >> 1, wn = wave & 1;

    __shared__ short As_hi[2][128 * APAD];
    __shared__ short As_lo[2][128 * APAD];
    __shared__ short Bh_hi[180 * BPAD];
    __shared__ short Bh_lo[180 * BPAD];
    __shared__ float wobj[3][128];

    for (int idx = tid; idx < 384; idx += 256) {
        int a = idx >> 7, m = idx & 127;
        wobj[a][m] = h.w1[(size_t)(a * 85 + 4) * C + co0 + m];
    }

    f32x4 acc[4][4];
    #pragma unroll
    for (int i = 0; i < 4; i++)
        #pragma unroll
        for (int j = 0; j < 4; j++) acc[i][j] = (f32x4){0.f, 0.f, 0.f, 0.f};

    // A staging slice for this thread: 2 units x {hi,lo}, unit=(m,q)
    const int am0 = tid >> 2, am1 = (256 + tid) >> 2;
    const int aq  = tid & 3;
    short8 pa_h[2], pa_l[2];
    auto loadA = [&](int ci0, int tap) {
        size_t o0 = ((size_t)(co0 + am0) * 9 + tap) * C + ci0 + aq * 8;
        size_t o1 = ((size_t)(co0 + am1) * 9 + tap) * C + ci0 + aq * 8;
        pa_h[0] = *(const short8*)(h.wh + o0);
        pa_l[0] = *(const short8*)(h.wl + o0);
        pa_h[1] = *(const short8*)(h.wh + o1);
        pa_l[1] = *(const short8*)(h.wl + o1);
    };
    auto storeA = [&](int b) {
        *(short8*)&As_hi[b][am0 * APAD + aq * 8] = pa_h[0];
        *(short8*)&As_lo[b][am0 * APAD + aq * 8] = pa_l[0];
        *(short8*)&As_hi[b][am1 * APAD + aq * 8] = pa_h[1];
        *(short8*)&As_lo[b][am1 * APAD + aq * 8] = pa_l[1];
    };

    // hood unit metadata (1440 units of 16B: 180 px x 4 q x {hi,lo})
    int um1[6], um2[6];
    #pragma unroll
    for (int i = 0; i < 6; i++) {
        int v = tid + (i << 8);
        int ok = (v < 1440) ? 1 : 0;
        int arr = (v >= 720) ? 1 : 0;
        int u = v - (arr ? 720 : 0);
        int hp = (u >> 2) % 180;
        int q = u & 3;
        int hy = hp / 18, hx = hp - hy * 18;
        int gy = py0 - 1 + hy, gx = px0 - 1 + hx;
        int inb = (ok && gy >= 0 && gy < H && gx >= 0 && gx < W) ? 1 : 0;
        int pix = inb ? (gy * W + gx) : 0;
        um1[i] = pix | (q << 20) | (arr << 22) | (inb << 23) | (ok << 24);
        um2[i] = hp * BPAD + q * 8;
    }
    int vb[4];
    #pragma unroll
    for (int nt = 0; nt < 4; nt++) {
        int n = wn * 64 + nt * 16 + l15;
        vb[nt] = ((n >> 4) * 18 + (n & 15)) * BPAD + quad * 8;
    }

    short8 hreg[6];
    auto load_units = [&](int ci0) {
        #pragma unroll
        for (int i = 0; i < 6; i++) {
            short8 r = {0,0,0,0,0,0,0,0};
            if ((um1[i] >> 23) & 1) {
                int pix = um1[i] & 0xFFFFF;
                int q   = (um1[i] >> 20) & 3;
                int arr = (um1[i] >> 22) & 1;
                if (use_xt) {
                    const short* gp = (arr ? h.xl : h.xh) + (size_t)pix * C + ci0 + q * 8;
                    r = *(const short8*)gp;
                } else {
                    const float* fp = h.x + (size_t)(ci0 + q * 8) * HW + pix;
                    #pragma unroll
                    for (int k = 0; k < 8; k++) {
                        float vv = fp[(size_t)k * HW];
                        short hh = f2bf(vv);
                        r[k] = arr ? f2bf(vv - bf2f(hh)) : hh;
                    }
                }
            }
            hreg[i] = r;
        }
    };

    load_units(0);
    loadA(0, 0);
    for (int ch = 0; ch < h.chunks; ++ch) {
        const int ci0 = ch << 5;
        // arrive here right after a barrier (kernel start or end-of-tap-8):
        // all reads of hood and A buffers are complete.
        #pragma unroll
        for (int i = 0; i < 6; i++) {
            if ((um1[i] >> 24) & 1) {
                short* dst = (((um1[i] >> 22) & 1) ? Bh_lo : Bh_hi) + um2[i];
                *(short8*)dst = hreg[i];
            }
        }
        storeA(0);            // A(tap0) -> buf0
        loadA(ci0, 1);        // pa <- A(tap1)
        __syncthreads();      // hood + A0 visible
        if (ch + 1 < h.chunks) load_units(ci0 + 32);   // next-chunk hood

        #pragma unroll
        for (int tap = 0; tap < 9; ++tap) {
            if (tap < 8) {
                storeA((tap + 1) & 1);                       // A(tap+1)
                if (tap < 7)                 loadA(ci0, tap + 2);
                else if (ch + 1 < h.chunks)  loadA(ci0 + 32, 0);
            }
            const int dy = tap / 3, dx = tap - dy * 3;
            const int hoff = (dy * 18 + dx) * BPAD;
            const int ab = tap & 1;
            short8 ah[4], al[4], bh[4], bl[4];
            #pragma unroll
            for (int mt = 0; mt < 4; mt++) {
                int ro = (wm * 64 + mt * 16 + l15) * APAD + quad * 8;
                ah[mt] = *(const short8*)&As_hi[ab][ro];
                al[mt] = *(const short8*)&As_lo[ab][ro];
            }
            #pragma unroll
            for (int nt = 0; nt < 4; nt++) {
                bh[nt] = *(const short8*)&Bh_hi[vb[nt] + hoff];
                bl[nt] = *(const short8*)&Bh_lo[vb[nt] + hoff];
            }
            #pragma unroll
            for (int mt = 0; mt < 4; mt++)
                #pragma unroll
                for (int nt = 0; nt < 4; nt++) {
                    acc[mt][nt] = __builtin_amdgcn_mfma_f32_16x16x32_bf16(ah[mt], bh[nt], acc[mt][nt], 0, 0, 0);
                    acc[mt][nt] = __builtin_amdgcn_mfma_f32_16x16x32_bf16(ah[mt], bl[nt], acc[mt][nt], 0, 0, 0);
                    acc[mt][nt] = __builtin_amdgcn_mfma_f32_16x16x32_bf16(al[mt], bh[nt], acc[mt][nt], 0, 0, 0);
                }
            __syncthreads();   // end-of-tap: protects A buf swap & (tap8) hood
        }
    }

    // ---- epilogue: y = acc + bias; fused objectness partial dot ----
    #pragma unroll
    for (int nt = 0; nt < 4; nt++) {
        int n = wn * 64 + nt * 16 + l15;
        int py = py0 + (n >> 4), px = px0 + (n & 15);
        if (px < W) {
            int p = py * W + px;
            float s0 = 0.f, s1 = 0.f, s2 = 0.f;
            #pragma unroll
            for (int mt = 0; mt < 4; mt++) {
                #pragma unroll
                for (int r = 0; r < 4; r++) {
                    int m = wm * 64 + mt * 16 + quad * 4 + r;
                    int co = co0 + m;
                    float yv = acc[mt][nt][r] + h.bias[co];
                    h.y[(size_t)co * HW + p] = yv;
                    s0 = fmaf(yv, wobj[0][m], s0);
                    s1 = fmaf(yv, wobj[1][m], s1);
                    s2 = fmaf(yv, wobj[2][m], s2);
                }
            }
            atomicAdd(&logits[h.lbase + p], s0);
            atomicAdd(&logits[h.lbase + HW + p], s1);
            atomicAdd(&logits[h.lbase + 2 * HW + p], s2);
        }
    }
}

// ---------------- keys: logits -> sigmoid -> sort key + histogram ------------
__global__ __launch_bounds__(256) void keys_kernel(
    const float* __restrict__ logits,
    const float* __restrict__ b10, const float* __restrict__ b11, const float* __restrict__ b12,
    u64* __restrict__ keys, u32* __restrict__ hist)
{
    int i = blockIdx.x * 256 + threadIdx.x;
    if (i >= NBOX) return;
    float bias;
    if (i < 4800)       bias = b10[(i / 1600) * 85 + 4];
    else if (i < 24000) bias = b11[((i - 4800) / 6400) * 85 + 4];
    else                bias = b12[((i - 24000) / 25600) * 85 + 4];
    float s = 1.0f / (1.0f + expf(-(logits[i] + bias)));
    u64 k = ((u64)__float_as_uint(s) << 32) | (u64)(0xFFFFFFFFu - (u32)i);
    keys[i] = k;
    atomicAdd(&hist[(u32)(k >> 48)], 1u);
}

// ---------------- top-256 selection: parallel 2-stage ----------------
__global__ __launch_bounds__(256) void select1_kernel(const u32* __restrict__ hist,
                                                      u32* __restrict__ csum2)
{
    __shared__ u32 red[256];
    int t = threadIdx.x;
    red[t] = hist[blockIdx.x * 256 + t];
    __syncthreads();
    for (int s = 128; s > 0; s >>= 1) {
        if (t < s) red[t] += red[t + s];
        __syncthreads();
    }
    if (t == 0) csum2[blockIdx.x] = red[0];
}

__global__ __launch_bounds__(256) void select2_kernel(const u32* __restrict__ hist,
                                                      const u32* __restrict__ csum2,
                                                      u32* __restrict__ meta)
{
    __shared__ u32 cs[256];
    __shared__ u32 hb[256];
    __shared__ int sh_chunk;
    __shared__ u32 sh_cum;
    int t = threadIdx.x;
    cs[t] = csum2[t];
    __syncthreads();
    if (t == 0) {
        u32 cum = 0; int chunk = 255;
        for (; chunk > 0; chunk--) {
            if (cum + cs[chunk] >= 256u) break;
            cum += cs[chunk];
        }
        sh_chunk = chunk; sh_cum = cum;
    }
    __syncthreads();
    hb[t] = hist[sh_chunk * 256 + t];
    __syncthreads();
    if (t == 0) {
        int chunk = sh_chunk;
        u32 cumAbove = sh_cum;
        int B = chunk * 256;
        for (int bb = 255; bb >= 0; bb--) {
            u32 hv = hb[bb];
            if (cumAbove + hv >= 256u) { B = chunk * 256 + bb; break; }
            cumAbove += hv;
        }
        meta[0] = (u32)B;
        meta[1] = cumAbove;
    }
}

__global__ __launch_bounds__(256) void compact_kernel(
    const u64* __restrict__ keys, int n, const u32* __restrict__ meta,
    u64* __restrict__ cand, u32* __restrict__ count)
{
    int i = blockIdx.x * blockDim.x + threadIdx.x;
    if (i < n) {
        u64 k = keys[i];
        if ((u32)(k >> 48) >= meta[0]) {
            u32 pos = atomicAdd(count, 1u);
            if (pos < CAND_CAP) cand[pos] = k;
        }
    }
}

__global__ __launch_bounds__(1024) void sort_select_kernel(
    const u64* __restrict__ cand, const u32* __restrict__ meta,
    u32* __restrict__ sel)
{
    __shared__ u64 sk[CAND_CAP];
    int n = (int)meta[2];
    if (n > CAND_CAP) n = CAND_CAP;
    for (int i = threadIdx.x; i < CAND_CAP; i += 1024)
        sk[i] = (i < n) ? cand[i] : 0ull;
    __syncthreads();
    for (int k = 2; k <= CAND_CAP; k <<= 1) {
        for (int j = k >> 1; j > 0; j >>= 1) {
            for (int i = threadIdx.x; i < CAND_CAP; i += 1024) {
                int ixj = i ^ j;
                if (ixj > i) {
                    u64 a = sk[i], c = sk[ixj];
                    bool sw = ((i & k) == 0) ? (a > c) : (a < c);
                    if (sw) { sk[i] = c; sk[ixj] = a; }
                }
            }
            __syncthreads();
        }
    }
    if (threadIdx.x < 256) {
        u64 k = sk[CAND_CAP - 1 - threadIdx.x];
        sel[threadIdx.x] = 0xFFFFFFFFu - (u32)(k & 0xFFFFFFFFull);
    }
}

// ----- final: 85-ch 1x1 conv + decode for winners, wave-per-channel GEMV -----
__global__ __launch_bounds__(256) void final_kernel(
    const float* __restrict__ y0, const float* __restrict__ y1, const float* __restrict__ y2,
    const float* __restrict__ w10, const float* __restrict__ w11, const float* __restrict__ w12,
    const float* __restrict__ b10, const float* __restrict__ b11, const float* __restrict__ b12,
    const u32* __restrict__ sel, float* __restrict__ out)
{
    int b = blockIdx.x;
    u32 bi = sel[b];
    const float *y, *w1, *b1;
    int C, H, W, base; float ratio;
    float anchs[6];
    if (bi < 4800u) {
        y = y0; w1 = w10; b1 = b10; C = 1024; H = 40; W = 40; base = 0; ratio = 32.f;
        anchs[0]=116.f; anchs[1]=90.f; anchs[2]=156.f; anchs[3]=198.f; anchs[4]=373.f; anchs[5]=326.f;
    } else if (bi < 24000u) {
        y = y1; w1 = w11; b1 = b11; C = 512; H = 80; W = 80; base = 4800; ratio = 16.f;
        anchs[0]=30.f; anchs[1]=61.f; anchs[2]=62.f; anchs[3]=45.f; anchs[4]=59.f; anchs[5]=119.f;
    } else {
        y = y2; w1 = w12; b1 = b12; C = 256; H = 160; W = 160; base = 24000; ratio = 8.f;
        anchs[0]=10.f; anchs[1]=13.f; anchs[2]=16.f; anchs[3]=30.f; anchs[4]=33.f; anchs[5]=23.f;
    }
    int HW = H * W;
    int r = (int)bi - base;
    int a = r / HW, p = r % HW;
    __shared__ float ys[1024];
    for (int ci = threadIdx.x; ci < C; ci += 256)
        ys[ci] = y[(size_t)ci * HW + p];
    __syncthreads();
    int wv = threadIdx.x >> 6, ln = threadIdx.x & 63;
    int py = p / W, px = p - (p / W) * W;
    for (int c = wv; c < 85; c += 4) {
        const float* wrow = w1 + (size_t)(a * 85 + c) * C;
        float s = 0.f;
        for (int ci = ln; ci < C; ci += 64) s = fmaf(ys[ci], wrow[ci], s);
        #pragma unroll
        for (int off = 32; off > 0; off >>= 1) s += __shfl_down(s, off, 64);
        if (ln == 0) {
            float v = s + b1[a * 85 + c];
            float sg = 1.0f / (1.0f + expf(-v));
            float o;
            if (c == 0)      o = (sg * 2.0f - 0.5f + (float)px) * ratio;
            else if (c == 1) o = (sg * 2.0f - 0.5f + (float)py) * ratio;
            else if (c == 2) { float t = sg * 2.0f; o = t * t * anchs[a * 2]; }
            else if (c == 3) { float t = sg * 2.0f; o = t * t * anchs[a * 2 + 1]; }
            else             o = sg;
            out[(size_t)b * 85 + c] = o;
        }
    }
}

// ---------------- launch ----------------
extern "C" void kernel_launch(void* const* d_in, const int* in_sizes, int n_in,
                              void* d_out, int out_size, void* d_ws, size_t ws_size,
                              hipStream_t stream)
{
    const float* feat0 = (const float*)d_in[0];   // (256,160,160)
    const float* feat1 = (const float*)d_in[1];   // (512,80,80)
    const float* feat2 = (const float*)d_in[2];   // (1024,40,40)
    const float* w3_0 = (const float*)d_in[3];  const float* b3_0 = (const float*)d_in[4];
    const float* w1_0 = (const float*)d_in[5];  const float* b1_0 = (const float*)d_in[6];
    const float* w3_1 = (const float*)d_in[7];  const float* b3_1 = (const float*)d_in[8];
    const float* w1_1 = (const float*)d_in[9];  const float* b1_1 = (const float*)d_in[10];
    const float* w3_2 = (const float*)d_in[11]; const float* b3_2 = (const float*)d_in[12];
    const float* w1_2 = (const float*)d_in[13]; const float* b1_2 = (const float*)d_in[14];

    char* ws = (char*)d_ws;
    short* wth0 = (short*)(ws + OFF_WTH0);
    short* wth1 = (short*)(ws + OFF_WTH1);
    short* wth2 = (short*)(ws + OFF_WTH2);
    short* wtl0 = (short*)(ws + OFF_WTL0);
    short* wtl1 = (short*)(ws + OFF_WTL1);
    short* wtl2 = (short*)(ws + OFF_WTL2);
    float* y0   = (float*)(ws + OFF_Y0);
    float* y1   = (float*)(ws + OFF_Y1);
    float* y2   = (float*)(ws + OFF_Y2);
    u64*   keys = (u64*)  (ws + OFF_KEYS);
    u32*   hist = (u32*)  (ws + OFF_HIST);
    u32*   meta = (u32*)  (ws + OFF_META);
    float* logits = (float*)(ws + OFF_LOG);
    u64*   cand = (u64*)  (ws + OFF_CAND);
    u32*   sel  = (u32*)  (ws + OFF_SEL);
    u32*   cs2  = (u32*)  (ws + OFF_CS2);

    const int use_xt = (ws_size >= NEED_FULL) ? 1 : 0;
    short* xth0 = (short*)(ws + OFF_XTH0);
    short* xth1 = (short*)(ws + OFF_XTH1);
    short* xth2 = (short*)(ws + OFF_XTH2);
    short* xtl0 = (short*)(ws + OFF_XTL0);
    short* xtl1 = (short*)(ws + OFF_XTL1);
    short* xtl2 = (short*)(ws + OFF_XTL2);

    hipMemsetAsync(ws + OFF_HIST, 0, MEMSET_LEN, stream);

    // merged prep: weights (blocks 0..5375) + input transpose (5376..16575)
    {
        PrepW pw0 = {w3_0, wth0, wtl0, 1024, 0};
        PrepW pw1 = {w3_1, wth1, wtl1, 512,  4096};
        PrepW pw2 = {w3_2, wth2, wtl2, 256,  5120};
        PrepXs px0 = {feat2, xth0, xtl0, 1024, 1600,  5376,  50};
        PrepXs px1 = {feat1, xth1, xtl1, 512,  6400,  6976,  200};
        PrepXs px2 = {feat0, xth2, xtl2, 256,  25600, 10176, 800};
        prep_all<<<16576, 256, 0, stream>>>(pw0, pw1, pw2, px0, px1, px2, use_xt);
    }

    // fused 3-head 3x3 conv (+ objectness partials)
    ConvHead h0 = {feat2, xth0, xtl0, wth0, wtl0, b3_0, w1_0, y0, 1024, 40,  40,  3,  7, 3, 32, 0,   0};
    ConvHead h1 = {feat1, xth1, xtl1, wth1, wtl1, b3_1, w1_1, y1, 512,  80,  80,  5,  3, 2, 16, 120, 4800};
    ConvHead h2 = {feat0, xth2, xtl2, wth2, wtl2, b3_2, w1_2, y2, 256,  160, 160, 10, 1, 1, 8,  320, 24000};
    conv3x3_mfma<<<720, 256, 0, stream>>>(h0, h1, h2, logits, use_xt);

    // keys + histogram from logits
    keys_kernel<<<(NBOX + 255) / 256, 256, 0, stream>>>(logits, b1_0, b1_1, b1_2, keys, hist);

    // top-256
    select1_kernel<<<256, 256, 0, stream>>>(hist, cs2);
    select2_kernel<<<1, 256, 0, stream>>>(hist, cs2, meta);
    compact_kernel<<<(NBOX + 255) / 256, 256, 0, stream>>>(keys, NBOX, meta, cand, meta + 2);
    sort_select_kernel<<<1, 1024, 0, stream>>>(cand, meta, sel);

    // full 85-channel compute + decode for winners only
    final_kernel<<<256, 256, 0, stream>>>(y0, y1, y2, w1_0, w1_1, w1_2,
                                          b1_0, b1_1, b1_2, sel, (float*)d_out);
}